// Round 2
// baseline (211.645 us; speedup 1.0000x reference)
//
#include <hip/hip_runtime.h>
#include <stdint.h>

typedef unsigned short u16;
typedef unsigned int u32;
typedef __attribute__((ext_vector_type(8))) short short8;
typedef __attribute__((ext_vector_type(4))) float f32x4;

#define L_IN   1323000
#define PAD    1024
#define HOP    441
#define T_FR   3001         // frames per (b,c) row
#define M_ROWS 24008        // 8 * 3001
#define K1     2048
#define K2     2560         // 5 taps * 512
#define W_2PI_N 3.0679615757712823e-3f   // 2*pi/2048

__device__ __forceinline__ u16 f2bf(float f) {
  union { float f; u32 u; } v; v.f = f;
  u32 r = v.u + 0x7FFFu + ((v.u >> 16) & 1u);   // RNE
  return (u16)(r >> 16);
}

__device__ __forceinline__ void gload16(const void* g, void* l) {
  __builtin_amdgcn_global_load_lds(
      (const __attribute__((address_space(1))) u32*)g,
      (__attribute__((address_space(3))) u32*)l, 16, 0, 0);
}

// ---------------- prep: fold hann into W_enc; build masked/rearranged W_dec ----------------

// wencb[m,n] = bf16(hann[n] * W_enc[m,n]);  b2[r, j*512+m] = bf16(W_dec[441j+r, m]) masked
__global__ void prep_wb(const float* __restrict__ W_enc, const float* __restrict__ W_dec,
                        u16* __restrict__ wencb, u16* __restrict__ b2,
                        float* __restrict__ zeros) {
  int stride = gridDim.x * blockDim.x;
  int tid0 = blockIdx.x * blockDim.x + threadIdx.x;
  for (int idx = tid0; idx < 64; idx += stride) zeros[idx] = 0.f;
  for (int idx = tid0; idx < 512 * 2048; idx += stride) {
    int n = idx & 2047;
    float w = 0.5f * (1.f - cosf(W_2PI_N * (float)n));
    wencb[idx] = f2bf(w * W_enc[idx]);
  }
  for (int idx = tid0; idx < 512 * 2560; idx += stride) {
    int r = idx / 2560;
    int k = idx - r * 2560;
    int j = k >> 9;
    int m = k & 511;
    int n = HOP * j + r;
    float v = (r < 441 && n < 2048) ? W_dec[n * 512 + m] : 0.f;
    b2[idx] = f2bf(v);
  }
}

// ---------------- shared MFMA core (128x128 tile, 4 waves, 2x2 wavegrid) ----------------

__device__ __forceinline__ void mfma_tile(const u16* sA, const u16* sB, f32x4 acc[4][4],
                                          int lane, int wr, int wc) {
  const int lr = lane & 15;
  const int lk = (lane >> 4) << 3;
  #pragma unroll
  for (int ks = 0; ks < 2; ++ks) {
    short8 af[4], bg[4];
    #pragma unroll
    for (int f = 0; f < 4; ++f)
      af[f] = *(const short8*)(sA + (wr + f * 16 + lr) * 64 + ks * 32 + lk);
    #pragma unroll
    for (int f = 0; f < 4; ++f)
      bg[f] = *(const short8*)(sB + (wc + f * 16 + lr) * 64 + ks * 32 + lk);
    #pragma unroll
    for (int mf = 0; mf < 4; ++mf)
      #pragma unroll
      for (int nf = 0; nf < 4; ++nf)
        acc[mf][nf] = __builtin_amdgcn_mfma_f32_16x16x32_bf16(af[mf], bg[nf], acc[mf][nf], 0, 0, 0);
  }
}

// ---------------- GEMM1: feat[24008,512] = frames @ (hann*W_enc)^T ----------------
// A is gathered straight from x with on-the-fly reflect padding (no xp buffer).

__global__ __launch_bounds__(256, 2)
void gemm_enc(const float* __restrict__ x, const u16* __restrict__ wencb,
              u16* __restrict__ featb) {
  __shared__ u16 sA[128 * 64];
  __shared__ u16 sB[128 * 64];
  const int tid = threadIdx.x;
  const int lane = tid & 63;
  const int w = tid >> 6;
  const int m0 = blockIdx.x * 128;
  const int n0 = blockIdx.y * 128;

  // B staging (global_load_lds, 4 insts/thread)
  const u16* bsrc[4];
  #pragma unroll
  for (int i = 0; i < 4; ++i) {
    int row = (i * 4 + w) * 8 + (lane >> 3);
    bsrc[i] = wencb + (size_t)(n0 + row) * 2048 + (lane & 7) * 8;
  }
  // A staging (reg-staged fp32 -> bf16), 4 chunks of 8 elems per thread
  int abase[4], aoff[4];
  const float* xrow[4];
  unsigned amask = 0;
  #pragma unroll
  for (int i = 0; i < 4; ++i) {
    int c = i * 256 + tid;            // chunk id 0..1023
    int row = c >> 3;
    int c8 = (c & 7) * 8;
    aoff[i] = row * 64 + c8;
    int rg = m0 + row;
    xrow[i] = x;
    abase[i] = 0;
    if (rg < M_ROWS) {
      amask |= 1u << i;
      int bc = rg / T_FR;
      int t  = rg - bc * T_FR;
      xrow[i] = x + (size_t)bc * L_IN;
      abase[i] = HOP * t + c8 - PAD;  // unpadded sample index of element 0
    }
  }

  f32x4 acc[4][4];
  #pragma unroll
  for (int a = 0; a < 4; ++a)
    #pragma unroll
    for (int b = 0; b < 4; ++b) acc[a][b] = f32x4{0.f, 0.f, 0.f, 0.f};

  const int wr = (w >> 1) * 64, wc = (w & 1) * 64;

  for (int kc = 0; kc < K1; kc += 64) {
    __syncthreads();
    #pragma unroll
    for (int i = 0; i < 4; ++i)
      gload16(bsrc[i] + kc, &sB[(i * 4 + w) * 512]);
    #pragma unroll
    for (int i = 0; i < 4; ++i) {
      float v[8];
      #pragma unroll
      for (int e = 0; e < 8; ++e) v[e] = 0.f;
      if (amask & (1u << i)) {
        const float* xr = xrow[i];
        int j0 = abase[i] + kc;
        if (j0 >= 0 && j0 <= L_IN - 8) {
          #pragma unroll
          for (int e = 0; e < 8; ++e) v[e] = xr[j0 + e];
        } else {
          #pragma unroll
          for (int e = 0; e < 8; ++e) {
            int j = j0 + e;
            int ja = j < 0 ? -j : j;
            int jb = 2 * L_IN - 2 - ja;
            int jr = ja < jb ? ja : jb;   // reflect (no edge repeat)
            v[e] = xr[jr];
          }
        }
      }
      u32 pk[4];
      #pragma unroll
      for (int e = 0; e < 4; ++e)
        pk[e] = (u32)f2bf(v[2 * e]) | ((u32)f2bf(v[2 * e + 1]) << 16);
      uint4 q; q.x = pk[0]; q.y = pk[1]; q.z = pk[2]; q.w = pk[3];
      *(uint4*)(&sA[aoff[i]]) = q;
    }
    __syncthreads();
    mfma_tile(sA, sB, acc, lane, wr, wc);
  }

  #pragma unroll
  for (int mf = 0; mf < 4; ++mf) {
    #pragma unroll
    for (int e = 0; e < 4; ++e) {
      int rg = m0 + wr + mf * 16 + ((lane >> 4) << 2) + e;
      if (rg < M_ROWS) {
        #pragma unroll
        for (int nf = 0; nf < 4; ++nf) {
          int cg = n0 + wc + nf * 16 + (lane & 15);
          featb[(size_t)rg * 512 + cg] = f2bf(acc[mf][nf][e]);
        }
      }
    }
  }
}

// ---------------- GEMM2: decode + overlap-add (im2col over 5 taps), fused epilogue ----------------

__global__ __launch_bounds__(256, 2)
void gemm_dec(const u16* __restrict__ featb, const u16* __restrict__ b2,
              const u16* __restrict__ zeros, float* __restrict__ out) {
  __shared__ u16 sA[128 * 64];
  __shared__ u16 sB[128 * 64];
  const int tid = threadIdx.x;
  const int lane = tid & 63;
  const int w = tid >> 6;
  const int m0 = blockIdx.x * 128;
  const int n0 = blockIdx.y * 128;
  const int col8 = (lane & 7) * 8;

  const u16* bsrc[4];
  const u16* fsrc[4];
  int qiv[4];
  unsigned vmask = 0;
  #pragma unroll
  for (int i = 0; i < 4; ++i) {
    int row = (i * 4 + w) * 8 + (lane >> 3);
    bsrc[i] = b2 + (size_t)(n0 + row) * 2560 + col8;
    int rg = m0 + row;
    int rgc = rg < M_ROWS ? rg : (M_ROWS - 1);
    int bc = rgc / T_FR;
    int qi = rgc - bc * T_FR;
    if (rg < M_ROWS) vmask |= 1u << i;
    qiv[i] = qi;
    fsrc[i] = featb + (size_t)(bc * T_FR + qi + 2) * 512 + col8;
  }

  f32x4 acc[4][4];
  #pragma unroll
  for (int a = 0; a < 4; ++a)
    #pragma unroll
    for (int b = 0; b < 4; ++b) acc[a][b] = f32x4{0.f, 0.f, 0.f, 0.f};

  const int wr = (w >> 1) * 64, wc = (w & 1) * 64;

  for (int kc = 0; kc < K2; kc += 64) {
    int j = kc >> 9;                  // tap index 0..4 (BK=64 never straddles a tap)
    __syncthreads();
    #pragma unroll
    for (int i = 0; i < 4; ++i)
      gload16(bsrc[i] + kc, &sB[(i * 4 + w) * 512]);
    #pragma unroll
    for (int i = 0; i < 4; ++i) {
      int t = qiv[i] + 2 - j;
      bool ok = ((vmask >> i) & 1) && (t >= 0) && (t <= 3000);
      const u16* pa = ok ? (fsrc[i] + kc - 1024 * j) : (zeros + col8);
      gload16(pa, &sA[(i * 4 + w) * 512]);
    }
    __syncthreads();
    mfma_tile(sA, sB, acc, lane, wr, wc);
  }

  // epilogue: (bc,qi,r) -> out index i = 441*qi + r - 142, scaled by 1/win_norm.
  // win_norm computed in-register: hann values depend only on (nf, j), shared across rows.
  const int lr16 = lane & 15;
  float hh[4][5];
  float rnfull[4];
  int cgv[4];
  #pragma unroll
  for (int nf = 0; nf < 4; ++nf) {
    int cg = n0 + wc + nf * 16 + lr16;
    cgv[nf] = cg;
    float s = 0.f;
    #pragma unroll
    for (int j = 0; j < 5; ++j) {
      int n = HOP * j + cg;
      float h = (cg < 441 && n < 2048) ? (0.5f - 0.5f * cosf(W_2PI_N * (float)n)) : 0.f;
      hh[nf][j] = h;
      s += h;
    }
    rnfull[nf] = 1.f / fmaxf(s, 1e-8f);
  }

  #pragma unroll
  for (int mf = 0; mf < 4; ++mf) {
    #pragma unroll
    for (int e = 0; e < 4; ++e) {
      int rg = m0 + wr + mf * 16 + ((lane >> 4) << 2) + e;
      if (rg < M_ROWS) {
        int bc = rg / T_FR;
        int qi = rg - bc * T_FR;
        int ib = HOP * qi - 142;
        bool interior = (qi >= 2) && (qi <= 2998);
        #pragma unroll
        for (int nf = 0; nf < 4; ++nf) {
          if (cgv[nf] < 441) {
            int oi = ib + cgv[nf];
            if (oi >= 0 && oi < L_IN) {
              float rn;
              if (interior) {
                rn = rnfull[nf];
              } else {
                float s = 0.f;
                #pragma unroll
                for (int j = 0; j < 5; ++j)
                  if ((unsigned)(qi + 2 - j) <= 3000u) s += hh[nf][j];
                rn = 1.f / fmaxf(s, 1e-8f);
              }
              out[(size_t)bc * L_IN + oi] = acc[mf][nf][e] * rn;
            }
          }
        }
      }
    }
  }
}

// ---------------- launch ----------------

extern "C" void kernel_launch(void* const* d_in, const int* in_sizes, int n_in,
                              void* d_out, int out_size, void* d_ws, size_t ws_size,
                              hipStream_t stream) {
  const float* x     = (const float*)d_in[0];
  const float* W_enc = (const float*)d_in[1];
  const float* W_dec = (const float*)d_in[2];
  float* out = (float*)d_out;
  char* ws = (char*)d_ws;

  // workspace layout (total 29,303,040 B ~= 27.9 MiB)
  u16*   wencb = (u16*)  (ws + 0);            // 512*2048*2  =  2,097,152
  u16*   b2    = (u16*)  (ws + 2097152);      // 512*2560*2  =  2,621,440
  u16*   featb = (u16*)  (ws + 4718592);      // 24008*512*2 = 24,584,192
  float* zeros = (float*)(ws + 29302784);     // 256 B zero block (gather redirect)

  prep_wb <<<2048, 256, 0, stream>>>(W_enc, W_dec, wencb, b2, zeros);
  gemm_enc<<<dim3(188, 4), 256, 0, stream>>>(x, wencb, featb);
  gemm_dec<<<dim3(188, 4), 256, 0, stream>>>(featb, b2, (const u16*)zeros, out);
}

// Round 5
// 152.652 us; speedup vs baseline: 1.3865x; 1.3865x over previous
//
#include <hip/hip_runtime.h>
#include <stdint.h>

typedef unsigned short u16;
typedef unsigned int u32;
typedef __attribute__((ext_vector_type(8))) short short8;
typedef __attribute__((ext_vector_type(4))) float f32x4;

#define L_IN   1323000
#define PAD    1024
#define HOP    441
#define T_FR   3001         // frames per (b,c) row
#define M_ROWS 24008        // 8 * 3001
#define NB     3008         // xb rows per bc (need 3005)
#define RPAD   448          // padded block row length (441 -> 448, 16B-aligned bf16 rows)
#define K1E    2240         // enc K: 5 taps * 448
#define K2     2560         // dec K: 5 taps * 512
#define W_2PI_N 3.0679615757712823e-3f   // 2*pi/2048

__device__ __forceinline__ u16 f2bf(float f) {
  union { float f; u32 u; } v; v.f = f;
  u32 r = v.u + 0x7FFFu + ((v.u >> 16) & 1u);   // RNE
  return (u16)(r >> 16);
}

__device__ __forceinline__ void gload16(const void* g, void* l) {
  __builtin_amdgcn_global_load_lds(
      (const __attribute__((address_space(1))) u32*)g,
      (__attribute__((address_space(3))) u32*)l, 16, 0, 0);
}

// ---------------- prep: blocked bf16 x, folded/rearranged weights ----------------
// xb[bc, u, r] = bf16(x_reflect[441u + r - 1024]), rows padded to 448
// wh2[m, 448j + r] = bf16(hann[441j+r] * W_enc[m, 441j+r])  (0 where r>=441 or n>=2048)
// b2[r, 512j + m]  = bf16(W_dec[441j+r, m])                 (0 where r>=441 or n>=2048)
__global__ void prep_all(const float* __restrict__ x,
                         const float* __restrict__ W_enc, const float* __restrict__ W_dec,
                         u16* __restrict__ xb, u16* __restrict__ wh2,
                         u16* __restrict__ b2, float* __restrict__ zeros) {
  int stride = gridDim.x * blockDim.x;
  int tid0 = blockIdx.x * blockDim.x + threadIdx.x;
  for (int idx = tid0; idx < 64; idx += stride) zeros[idx] = 0.f;
  for (int idx = tid0; idx < 8 * NB * RPAD; idx += stride) {
    int bc = idx / (NB * RPAD);
    int rem = idx - bc * (NB * RPAD);
    int u = rem / RPAD;
    int r = rem - u * RPAD;
    int s = HOP * u + r - PAD;
    int ja = s < 0 ? -s : s;
    int jb = 2 * L_IN - 2 - ja;
    int jr = ja < jb ? ja : jb;          // reflect (no edge repeat)
    xb[idx] = f2bf(x[(size_t)bc * L_IN + jr]);
  }
  for (int idx = tid0; idx < 512 * K1E; idx += stride) {
    int m = idx / K1E;
    int k = idx - m * K1E;
    int j = k / RPAD;
    int r = k - j * RPAD;
    int n = HOP * j + r;
    float v = 0.f;
    if (r < HOP && n < 2048)
      v = (0.5f - 0.5f * cosf(W_2PI_N * (float)n)) * W_enc[m * 2048 + n];
    wh2[idx] = f2bf(v);
  }
  for (int idx = tid0; idx < 512 * K2; idx += stride) {
    int r = idx / K2;
    int k = idx - r * K2;
    int j = k >> 9;
    int m = k & 511;
    int n = HOP * j + r;
    float v = (r < HOP && n < 2048) ? W_dec[n * 512 + m] : 0.f;
    b2[idx] = f2bf(v);
  }
}

// ---------------- shared MFMA core (128x128 tile, 4 waves, 2x2 wavegrid) ----------------
// LDS chunk (row, c) holds global chunk c ^ (row&7)  (staged via pre-swizzled source);
// reader wants global chunk ks*4+hi of row R -> reads LDS chunk (ks*4+hi) ^ (R&7).
__device__ __forceinline__ void mfma_tile(const u16* sA, const u16* sB, f32x4 acc[4][4],
                                          int lane, int wr, int wc) {
  const int lr = lane & 15;
  const int hi = lane >> 4;
  #pragma unroll
  for (int ks = 0; ks < 2; ++ks) {
    const int off = (((ks * 4 + hi) ^ (lr & 7)) << 3);   // swizzled chunk, u16 elements
    short8 af[4], bg[4];
    #pragma unroll
    for (int f = 0; f < 4; ++f)
      af[f] = *(const short8*)(sA + (wr + f * 16 + lr) * 64 + off);
    #pragma unroll
    for (int f = 0; f < 4; ++f)
      bg[f] = *(const short8*)(sB + (wc + f * 16 + lr) * 64 + off);
    #pragma unroll
    for (int mf = 0; mf < 4; ++mf)
      #pragma unroll
      for (int nf = 0; nf < 4; ++nf)
        acc[mf][nf] = __builtin_amdgcn_mfma_f32_16x16x32_bf16(af[mf], bg[nf], acc[mf][nf], 0, 0, 0);
  }
}

// ---------------- GEMM1: feat[24008,512] = xb-frames @ wh2^T ----------------
// Thanks to the 448-padding, the 5-tap im2col collapses to A-row stride 448:
// A[t, kc + e] = xb[(bc*NB + t)*448 + kc + e]  -- plain GEMM, all gload16.

__global__ __launch_bounds__(256, 2)
void gemm_enc(const u16* __restrict__ xb, const u16* __restrict__ wh2,
              u16* __restrict__ featb) {
  __shared__ u16 sA[128 * 64];
  __shared__ u16 sB[128 * 64];
  const int tid = threadIdx.x;
  const int lane = tid & 63;
  const int w = tid >> 6;
  const int m0 = blockIdx.x * 128;
  const int n0 = blockIdx.y * 128;
  const int colsw = (((lane & 7) ^ ((lane >> 3) & 7)) << 3);  // pre-swizzled source chunk

  const u16* bsrc[4];
  const u16* asrc[4];
  #pragma unroll
  for (int i = 0; i < 4; ++i) {
    int row = (i * 4 + w) * 8 + (lane >> 3);
    bsrc[i] = wh2 + (size_t)(n0 + row) * K1E + colsw;
    int rg = m0 + row;
    int rgc = rg < M_ROWS ? rg : (M_ROWS - 1);
    int bc = rgc / T_FR;
    int t  = rgc - bc * T_FR;
    asrc[i] = xb + ((size_t)bc * NB + t) * RPAD + colsw;
  }

  f32x4 acc[4][4];
  #pragma unroll
  for (int a = 0; a < 4; ++a)
    #pragma unroll
    for (int b = 0; b < 4; ++b) acc[a][b] = f32x4{0.f, 0.f, 0.f, 0.f};

  const int wr = (w >> 1) * 64, wc = (w & 1) * 64;

  for (int kc = 0; kc < K1E; kc += 64) {
    __syncthreads();
    #pragma unroll
    for (int i = 0; i < 4; ++i)
      gload16(bsrc[i] + kc, &sB[(i * 4 + w) * 512]);
    #pragma unroll
    for (int i = 0; i < 4; ++i)
      gload16(asrc[i] + kc, &sA[(i * 4 + w) * 512]);
    __syncthreads();
    mfma_tile(sA, sB, acc, lane, wr, wc);
  }

  #pragma unroll
  for (int mf = 0; mf < 4; ++mf) {
    #pragma unroll
    for (int e = 0; e < 4; ++e) {
      int rg = m0 + wr + mf * 16 + ((lane >> 4) << 2) + e;
      if (rg < M_ROWS) {
        #pragma unroll
        for (int nf = 0; nf < 4; ++nf) {
          int cg = n0 + wc + nf * 16 + (lane & 15);
          featb[(size_t)rg * 512 + cg] = f2bf(acc[mf][nf][e]);
        }
      }
    }
  }
}

// ---------------- GEMM2: decode + overlap-add (im2col over 5 taps), fused epilogue ----------------

__global__ __launch_bounds__(256, 2)
void gemm_dec(const u16* __restrict__ featb, const u16* __restrict__ b2,
              const u16* __restrict__ zeros, float* __restrict__ out) {
  __shared__ u16 sA[128 * 64];
  __shared__ u16 sB[128 * 64];
  const int tid = threadIdx.x;
  const int lane = tid & 63;
  const int w = tid >> 6;
  const int m0 = blockIdx.x * 128;
  const int n0 = blockIdx.y * 128;
  const int colsw = (((lane & 7) ^ ((lane >> 3) & 7)) << 3);

  const u16* bsrc[4];
  const u16* fsrc[4];
  int qiv[4];
  unsigned vmask = 0;
  #pragma unroll
  for (int i = 0; i < 4; ++i) {
    int row = (i * 4 + w) * 8 + (lane >> 3);
    bsrc[i] = b2 + (size_t)(n0 + row) * K2 + colsw;
    int rg = m0 + row;
    int rgc = rg < M_ROWS ? rg : (M_ROWS - 1);
    int bc = rgc / T_FR;
    int qi = rgc - bc * T_FR;
    if (rg < M_ROWS) vmask |= 1u << i;
    qiv[i] = qi;
    fsrc[i] = featb + (size_t)(bc * T_FR + qi + 2) * 512 + colsw;
  }

  f32x4 acc[4][4];
  #pragma unroll
  for (int a = 0; a < 4; ++a)
    #pragma unroll
    for (int b = 0; b < 4; ++b) acc[a][b] = f32x4{0.f, 0.f, 0.f, 0.f};

  const int wr = (w >> 1) * 64, wc = (w & 1) * 64;

  for (int kc = 0; kc < K2; kc += 64) {
    int j = kc >> 9;                  // tap index 0..4 (BK=64 never straddles a tap)
    __syncthreads();
    #pragma unroll
    for (int i = 0; i < 4; ++i)
      gload16(bsrc[i] + kc, &sB[(i * 4 + w) * 512]);
    #pragma unroll
    for (int i = 0; i < 4; ++i) {
      int t = qiv[i] + 2 - j;
      bool ok = ((vmask >> i) & 1) && (t >= 0) && (t <= 3000);
      const u16* pa = ok ? (fsrc[i] + kc - 1024 * j) : (zeros + colsw);
      gload16(pa, &sA[(i * 4 + w) * 512]);
    }
    __syncthreads();
    mfma_tile(sA, sB, acc, lane, wr, wc);
  }

  // epilogue: (bc,qi,r) -> out index i = 441*qi + r - 142, scaled by 1/win_norm.
  const int lr16 = lane & 15;
  float hh[4][5];
  float rnfull[4];
  int cgv[4];
  #pragma unroll
  for (int nf = 0; nf < 4; ++nf) {
    int cg = n0 + wc + nf * 16 + lr16;
    cgv[nf] = cg;
    float s = 0.f;
    #pragma unroll
    for (int j = 0; j < 5; ++j) {
      int n = HOP * j + cg;
      float h = (cg < HOP && n < 2048) ? (0.5f - 0.5f * cosf(W_2PI_N * (float)n)) : 0.f;
      hh[nf][j] = h;
      s += h;
    }
    rnfull[nf] = 1.f / fmaxf(s, 1e-8f);
  }

  #pragma unroll
  for (int mf = 0; mf < 4; ++mf) {
    #pragma unroll
    for (int e = 0; e < 4; ++e) {
      int rg = m0 + wr + mf * 16 + ((lane >> 4) << 2) + e;
      if (rg < M_ROWS) {
        int bc = rg / T_FR;
        int qi = rg - bc * T_FR;
        int ib = HOP * qi - 142;
        bool interior = (qi >= 2) && (qi <= 2998);
        #pragma unroll
        for (int nf = 0; nf < 4; ++nf) {
          if (cgv[nf] < HOP) {
            int oi = ib + cgv[nf];
            if (oi >= 0 && oi < L_IN) {
              float rn;
              if (interior) {
                rn = rnfull[nf];
              } else {
                float s = 0.f;
                #pragma unroll
                for (int j = 0; j < 5; ++j)
                  if ((unsigned)(qi + 2 - j) <= 3000u) s += hh[nf][j];
                rn = 1.f / fmaxf(s, 1e-8f);
              }
              out[(size_t)bc * L_IN + oi] = acc[mf][nf][e] * rn;
            }
          }
        }
      }
    }
  }
}

// ---------------- launch ----------------

extern "C" void kernel_launch(void* const* d_in, const int* in_sizes, int n_in,
                              void* d_out, int out_size, void* d_ws, size_t ws_size,
                              hipStream_t stream) {
  const float* x     = (const float*)d_in[0];
  const float* W_enc = (const float*)d_in[1];
  const float* W_dec = (const float*)d_in[2];
  float* out = (float*)d_out;
  char* ws = (char*)d_ws;

  // xb lives in d_out (21,561,344 B < 42,336,000 B): written by prep, read by enc,
  // then gemm_dec's epilogue bijectively overwrites every d_out element last.
  u16* xb = (u16*)d_out;

  // workspace layout (total 29,499,648 B ~= 28.1 MiB)
  u16*   wh2   = (u16*)  (ws + 0);            // 512*2240*2  =  2,293,760
  u16*   b2    = (u16*)  (ws + 2293760);      // 512*2560*2  =  2,621,440
  u16*   featb = (u16*)  (ws + 4915200);      // 24008*512*2 = 24,584,192
  float* zeros = (float*)(ws + 29499392);     // 256 B zero block (gather redirect)

  prep_all<<<2048, 256, 0, stream>>>(x, W_enc, W_dec, xb, wh2, b2, zeros);
  gemm_enc<<<dim3(188, 4), 256, 0, stream>>>(xb, wh2, featb);
  gemm_dec<<<dim3(188, 4), 256, 0, stream>>>(featb, b2, (const u16*)zeros, out);
}